// Round 15
// baseline (351.309 us; speedup 1.0000x reference)
//
#include <hip/hip_runtime.h>
#include <cstdint>

typedef __attribute__((ext_vector_type(8))) short bf16x8;
typedef __attribute__((ext_vector_type(4))) short bf16x4;
typedef __attribute__((ext_vector_type(4))) float f32x4;

#define S_LEN 4096
#define CDIM  640
#define NPROJ 5760

// K=16 bf16 MFMA (v_mfma_f32_16x16x16_bf16, gfx950-valid per ISA §10).
__device__ __forceinline__ f32x4 mfma16(bf16x4 a, bf16x4 b, f32x4 c){
#if defined(__HIP_DEVICE_COMPILE__) && __HIP_DEVICE_COMPILE__
  return __builtin_amdgcn_mfma_f32_16x16x16bf16_1k(a, b, c, 0, 0, 0);
#else
  (void)a; (void)b;
  return c;
#endif
}

// s_setprio wants a LITERAL: template param keeps it compile-time constant.
template<int P>
__device__ __forceinline__ void setprio(){
#if defined(__HIP_DEVICE_COMPILE__) && __HIP_DEVICE_COMPILE__
  __builtin_amdgcn_s_setprio(P);
#endif
}

// async global->LDS, 16B per lane; LDS dest must be wave-uniform base + lane*16
__device__ __forceinline__ void gload_lds(const unsigned short* g, unsigned short* l){
#if defined(__HIP_DEVICE_COMPILE__) && __HIP_DEVICE_COMPILE__
  __builtin_amdgcn_global_load_lds((const __attribute__((address_space(1))) unsigned int*)g,
                                   (__attribute__((address_space(3))) unsigned int*)l, 16, 0, 0);
#else
  (void)g; (void)l;
#endif
}

__device__ __forceinline__ unsigned short f2bf(float f){
  union { float f; uint32_t u; } v; v.f = f;
  uint32_t u = v.u;
  return (unsigned short)((u + 0x7fffu + ((u >> 16) & 1u)) >> 16);
}
__device__ __forceinline__ float b2f(unsigned short h){
  union { uint32_t u; float f; } v; v.u = ((uint32_t)h) << 16;
  return v.f;
}

// T1 XCD-chunked remap: HW assigns dispatch index d to XCD d%8 round-robin;
// remap so each XCD executes a CONTIGUOUS chunk of original tile ids
// (L2 reuse of shared operand panels). Requires nwg % 8 == 0 (all our grids).
__device__ __forceinline__ int xcd_chunk(int d, int nwg){
  return (d & 7) * (nwg >> 3) + (d >> 3);
}

// ---------------- R21: fused prologue (was k_labels/k_hist/k_perm/k_tiles).
__global__ __launch_bounds__(1024) void k_prep(const int* __restrict__ mask,
                                               const int* __restrict__ inp,
                                               int* __restrict__ labels,
                                               int* __restrict__ perm,
                                               int* __restrict__ inv,
                                               int* __restrict__ labP,
                                               int4* __restrict__ qtinfo,
                                               float* __restrict__ rowsum){
  __shared__ int h[4], base[5], cnt4[4], nkt[32];
  int t = threadIdx.x;
  if (t < 4){ h[t] = 0; cnt4[t] = 0; }
  __syncthreads();
  // labels + histogram
  for (int s = t; s < S_LEN; s += 1024){
    int y = s >> 6, x = s & 63;
    int off = (y * 8) * 512 + x * 8;
    int m = mask[off] & 0xff;
    int o = (inp[off] == 0) ? 0x100 : 0;
    labels[s] = m | o;
    atomicAdd(&h[m & 3], 1);
  }
  __syncthreads();
  if (t == 0){
    int a = 0;
    for (int c = 0; c < 4; c++){ base[c] = a; a += h[c]; }
    base[4] = a;
  }
  __syncthreads();
  // bucket-sort permutation (arrival order within bucket, same as before)
  for (int s = t; s < S_LEN; s += 1024){
    int lab = labels[s];
    int c = lab & 3;
    int pos = base[c] + atomicAdd(&cnt4[c], 1);
    perm[pos] = s; inv[s] = pos; labP[pos] = lab;
  }
  __syncthreads();   // labP globally visible within block
  // per-128-tile key ranges
  if (t < 32){
    int c0 = labP[t * 128] & 3, c1 = labP[t * 128 + 127] & 3;
    int lo = base[c0] & ~127, hi = (base[c1 + 1] + 127) & ~127;
    qtinfo[t].x = lo; qtinfo[t].y = hi; qtinfo[t].w = 0;
    nkt[t] = (hi - lo) >> 7;
  }
  __syncthreads();
  if (t == 0){
    int a = 0;
    for (int i = 0; i < 32; i++){ qtinfo[i].z = a; a += nkt[i]; }
  }
  for (int s = t; s < S_LEN; s += 1024) rowsum[s] = 0.f;
}

// ---------------- R24: fused f32 -> bf16 converts (hs + weights, one launch)
struct WPtrs { const float* w[10]; };

__global__ void k_cvt_all(const float* __restrict__ hs, WPtrs p,
                          unsigned short* __restrict__ hsb,
                          unsigned short* __restrict__ wall){
  int b = blockIdx.x;
  if (b < 2560){
    int idx = (b * 256 + threadIdx.x) * 4;          // 4096*640 exactly
    float4 v = *(const float4*)(hs + idx);
    ushort4 o;
    o.x = f2bf(v.x); o.y = f2bf(v.y); o.z = f2bf(v.z); o.w = f2bf(v.w);
    *(ushort4*)(hsb + idx) = o;
  } else {
    int e = ((b - 2560) * 256 + threadIdx.x) * 4;   // 10*409600 exactly
    int a = e / 409600, r = e % 409600;
    float sc = (a == 0 || a == 6) ? 0.11180339887498948f   // 1/sqrt(80)
             : (a == 3 ? 0.03952847075210474f : 1.0f);     // 1/sqrt(640)
    float4 v = *(const float4*)(p.w[a] + r);
    ushort4 o;
    o.x = f2bf(v.x * sc); o.y = f2bf(v.y * sc); o.z = f2bf(v.z * sc); o.w = f2bf(v.w * sc);
    *(ushort4*)(wall + e) = o;
  }
}

// ---------------- 128x128 MFMA GEMM
// BK=64, pitch-64 LDS, gload_lds staging. T1 XCD-chunked tile remap --
// consecutive tiles (sharing the A row-panel) land on the same XCD's L2.
template<int EPI>
__global__ __launch_bounds__(256) void k_gemm(const unsigned short* __restrict__ A,
                                              const unsigned short* __restrict__ B,
                                              int M, int N, int K, int ldc,
                                              const int* __restrict__ rowmap,
                                              unsigned short* __restrict__ Cb,
                                              float* __restrict__ Cf,
                                              const float* __restrict__ resid){
  __shared__ __align__(16) unsigned short As[128 * 64];
  __shared__ __align__(16) unsigned short Bs[128 * 64];
  int d = blockIdx.y * gridDim.x + blockIdx.x;
  int o = xcd_chunk(d, gridDim.x * gridDim.y);
  int m0 = (o / gridDim.x) * 128, n0 = (o % gridDim.x) * 128;
  int tid = threadIdx.x;
  int wid = tid >> 6, lane = tid & 63;
  int quad = lane >> 4, l16 = lane & 15;
  int wm = (wid >> 1) * 64, wn = (wid & 1) * 64;
  f32x4 acc[4][4];
#pragma unroll
  for (int i = 0; i < 4; i++)
#pragma unroll
    for (int j = 0; j < 4; j++) acc[i][j] = f32x4{0.f, 0.f, 0.f, 0.f};

  for (int k0 = 0; k0 < K; k0 += 64){
    __syncthreads();
#pragma unroll
    for (int u = 0; u < 4; u++){
      int c = tid + u * 256;
      int row = c >> 3, off = (c & 7) * 8;
      gload_lds(&A[(size_t)(m0 + row) * K + k0 + off], &As[c * 8]);
      gload_lds(&B[(size_t)(n0 + row) * K + k0 + off], &Bs[c * 8]);
    }
    __syncthreads();
#pragma unroll
    for (int ks = 0; ks < 2; ks++){
      bf16x8 af[4], bfr[4];
#pragma unroll
      for (int t = 0; t < 4; t++){
        af[t]  = *(const bf16x8*)(&As[(wm + t * 16 + l16) * 64 + ks * 32 + quad * 8]);
        bfr[t] = *(const bf16x8*)(&Bs[(wn + t * 16 + l16) * 64 + ks * 32 + quad * 8]);
      }
#pragma unroll
      for (int mt = 0; mt < 4; mt++)
#pragma unroll
        for (int nt = 0; nt < 4; nt++)
          acc[mt][nt] = __builtin_amdgcn_mfma_f32_16x16x32_bf16(af[mt], bfr[nt], acc[mt][nt], 0, 0, 0);
    }
  }
#pragma unroll
  for (int mt = 0; mt < 4; mt++)
#pragma unroll
    for (int nt = 0; nt < 4; nt++)
#pragma unroll
      for (int r = 0; r < 4; r++){
        int row = m0 + wm + mt * 16 + quad * 4 + r;
        int col = n0 + wn + nt * 16 + l16;
        float v = acc[mt][nt][r];
        if (EPI == 0){
          Cb[(size_t)rowmap[row] * ldc + col] = f2bf(v);
        } else {
          int ro = rowmap[row];
          Cf[(size_t)ro * ldc + col] = v + resid[(size_t)ro * ldc + col];
        }
      }
}

// ---------------- transpose the three V projections: vT[z][c][s]
// uint2-vectorized both sides (R21). Streaming, no inter-block reuse -> no swizzle.
__global__ void k_transpose_v(const unsigned short* __restrict__ proj, unsigned short* __restrict__ vT){
  __shared__ unsigned short T[64][68];
  int z = blockIdx.z;
  int s0 = blockIdx.x * 64, c0 = blockIdx.y * 64;
  int colbase = 1280 + z * 1920 + c0;   // v:1280  v_e:3200  v_o:5120
  unsigned short* dst = vT + (size_t)z * CDIM * S_LEN;
  int tid = threadIdx.x;
#pragma unroll
  for (int u = 0; u < 4; u++){
    int i = tid + u * 256;               // 1024 uint2 units: r = i>>4, c4 = (i&15)*4
    int r = i >> 4, c4 = (i & 15) * 4;
    uint2 v = *(const uint2*)&proj[(size_t)(s0 + r) * NPROJ + colbase + c4];
    *(uint2*)&T[r][c4] = v;
  }
  __syncthreads();
#pragma unroll
  for (int u = 0; u < 4; u++){
    int j = tid + u * 256;               // c = j>>4, r4 = (j&15)*4
    int c = j >> 4, r4 = (j & 15) * 4;
    ushort4 o;
    o.x = T[r4 + 0][c]; o.y = T[r4 + 1][c];
    o.z = T[r4 + 2][c]; o.w = T[r4 + 3][c];
    *(ushort4*)&dst[(size_t)(c0 + c) * S_LEN + s0 + r4] = o;
  }
}

// ---------------- flash attention, d=80, z=0: orig, z=1: outside
// R23 config + T5 s_setprio(1) around the two MFMA clusters (QK, PV).
// 3 blocks/CU x 8 waves at independent phases -> scheduler can favor
// MFMA-entering waves over staging/exp waves (m191-positive regime).
#define KP 84
#define VP 76
__global__ __launch_bounds__(512, 2) void k_attn80(const unsigned short* __restrict__ proj,
                                                   const unsigned short* __restrict__ vT,
                                                   const int* __restrict__ labP,
                                                   const int4* __restrict__ qtinfo,
                                                   unsigned short* __restrict__ opart,
                                                   float* __restrict__ lpP){
  __shared__ __align__(16) unsigned short Ks[2][64 * KP];
  __shared__ __align__(16) unsigned short Vt[2][80 * VP];
  __shared__ __align__(16) int labk[2][64];
  int tid = threadIdx.x, wid = tid >> 6, lane = tid & 63;
  int quad = lane >> 4, l16 = lane & 15;
  // T1 remap over the flattened grid (x fastest in dispatch order)
  int d = (int)(blockIdx.z * gridDim.y + blockIdx.y) * gridDim.x + blockIdx.x;
  int og = xcd_chunk(d, (int)(gridDim.x * gridDim.y * gridDim.z));
  int bx = og % gridDim.x;
  int by = (og / gridDim.x) % gridDim.y;
  int bz = og / (gridDim.x * gridDim.y);
  int qt = bx / 3, third = bx % 3;
  int q0 = qt * 256;
  int h  = by;
  bool OUTSIDE = (bz == 1);
  int qc = (OUTSIDE ? 3840 : 0) + h * 80;
  int kc = (OUTSIDE ? 4480 : 640) + h * 80;
  const unsigned short* vTb = vT + (size_t)(OUTSIDE ? 2 : 0) * CDIM * S_LEN;
  int4 qa = qtinfo[qt * 2], qb = qtinfo[qt * 2 + 1];
  int lo = min(qa.x, qb.x), hi = max(qa.y, qb.y);
  int t0 = lo >> 6, t1 = hi >> 6;
  int nt = t1 - t0;
  int ta = t0 + (nt * third) / 3;
  int tb = t0 + (nt * (third + 1)) / 3;

  // two query sets per wave (B-operand layout: lane n=l16 is the query, k=quad*4+j)
  int qrow0 = q0 + wid * 32 + l16;
  int qrow1 = qrow0 + 16;
  bf16x4 qf0[5], qf1[5];
#pragma unroll
  for (int dc = 0; dc < 5; dc++){
    qf0[dc] = *(const bf16x4*)&proj[(size_t)qrow0 * NPROJ + qc + dc * 16 + quad * 4];
    qf1[dc] = *(const bf16x4*)&proj[(size_t)qrow1 * NPROJ + qc + dc * 16 + quad * 4];
  }
  int lq0 = labP[qrow0] & 0xff, lq1 = labP[qrow1] & 0xff;

  float lp0 = 0.f, lp1 = 0.f;
  f32x4 Oc0[5], Oc1[5];
#pragma unroll
  for (int t = 0; t < 5; t++){ Oc0[t] = f32x4{0.f,0.f,0.f,0.f}; Oc1[t] = f32x4{0.f,0.f,0.f,0.f}; }

  // staging roles: waves 0-3 stage the K tile (64 rows x 20 uint2), waves 4-7
  // stage the V tile (80 rows x 16 uint2). 1280 uint2 per role over 256
  // threads = 5 units/thread; unit c = t5 + u*256. All tile-invariant.
  const bool ISK = (tid < 256);
  const int t5 = ISK ? tid : (tid - 256);
  const unsigned short* gb = ISK ? proj : vTb;
  const int km = ISK ? NPROJ : 1;                    // per-tile offset multiplier
  int ga0, ga1, ga2, ga3, ga4, ls0, ls1, ls2, ls3, ls4;
  {
    const int c0_ = t5, c1_ = t5 + 256, c2_ = t5 + 512, c3_ = t5 + 768, c4_ = t5 + 1024;
    if (ISK){
      ga0 = (c0_ / 20) * NPROJ + kc + (c0_ % 20) * 4;
      ga1 = (c1_ / 20) * NPROJ + kc + (c1_ % 20) * 4;
      ga2 = (c2_ / 20) * NPROJ + kc + (c2_ % 20) * 4;
      ga3 = (c3_ / 20) * NPROJ + kc + (c3_ % 20) * 4;
      ga4 = (c4_ / 20) * NPROJ + kc + (c4_ % 20) * 4;
      ls0 = (c0_ / 20) * KP + (c0_ % 20) * 4;
      ls1 = (c1_ / 20) * KP + (c1_ % 20) * 4;
      ls2 = (c2_ / 20) * KP + (c2_ % 20) * 4;
      ls3 = (c3_ / 20) * KP + (c3_ % 20) * 4;
      ls4 = (c4_ / 20) * KP + (c4_ % 20) * 4;
    } else {
      ga0 = (h * 80 + (c0_ >> 4)) * S_LEN + (c0_ & 15) * 4;
      ga1 = (h * 80 + (c1_ >> 4)) * S_LEN + (c1_ & 15) * 4;
      ga2 = (h * 80 + (c2_ >> 4)) * S_LEN + (c2_ & 15) * 4;
      ga3 = (h * 80 + (c3_ >> 4)) * S_LEN + (c3_ & 15) * 4;
      ga4 = (h * 80 + (c4_ >> 4)) * S_LEN + (c4_ & 15) * 4;
      ls0 = (c0_ >> 4) * VP + (c0_ & 15) * 4;
      ls1 = (c1_ >> 4) * VP + (c1_ & 15) * 4;
      ls2 = (c2_ >> 4) * VP + (c2_ & 15) * 4;
      ls3 = (c3_ >> 4) * VP + (c3_ & 15) * 4;
      ls4 = (c4_ >> 4) * VP + (c4_ & 15) * 4;
    }
  }

  uint2 r0, r1, r2, r3, r4;
  int lreg = 0;

#define LOADT(kt_) do {                                              \
    size_t _ob = (size_t)((kt_) * 64) * (size_t)km;                  \
    r0 = *(const uint2*)&gb[_ob + ga0];                              \
    r1 = *(const uint2*)&gb[_ob + ga1];                              \
    r2 = *(const uint2*)&gb[_ob + ga2];                              \
    r3 = *(const uint2*)&gb[_ob + ga3];                              \
    r4 = *(const uint2*)&gb[_ob + ga4];                              \
    if (tid < 64) lreg = labP[(kt_) * 64 + tid];                     \
  } while (0)

#define WRITET(b) do {                                               \
    unsigned short* _lb = ISK ? Ks[b] : Vt[b];                       \
    *(uint2*)&_lb[ls0] = r0;                                         \
    *(uint2*)&_lb[ls1] = r1;                                         \
    *(uint2*)&_lb[ls2] = r2;                                         \
    *(uint2*)&_lb[ls3] = r3;                                         \
    *(uint2*)&_lb[ls4] = r4;                                         \
    if (tid < 64) labk[b][tid] = lreg;                               \
  } while (0)

  if (ta < tb){
    // prologue: stage tile ta into buf0, issue loads for ta+1
    LOADT(ta);
    WRITET(0);
    if (ta + 1 < tb) LOADT(ta + 1);
    __syncthreads();

    int cur = 0;
    for (int kt = ta; kt < tb; kt++){
      int nxt = cur ^ 1;
      // regs hold tile kt+1: write it to the other buffer (its readers finished
      // at the barrier that ended iteration kt-1), then issue loads for kt+2.
      if (kt + 1 < tb){
        WRITET(nxt);
        if (kt + 2 < tb) LOADT(kt + 2);
      }

#pragma unroll
      for (int kg = 0; kg < 4; kg++){
        // S^T(16 keys x 16 queries) = K * Q^T, two query sets share kf
        f32x4 sa0 = f32x4{0.f,0.f,0.f,0.f}, sa1 = f32x4{0.f,0.f,0.f,0.f};
        setprio<1>();
#pragma unroll
        for (int dc = 0; dc < 5; dc++){
          bf16x4 kf = *(const bf16x4*)&Ks[cur][(kg * 16 + l16) * KP + dc * 16 + quad * 4];
          sa0 = mfma16(kf, qf0[dc], sa0);
          sa1 = mfma16(kf, qf1[dc], sa1);
        }
        setprio<0>();
        int4 lk4 = *(const int4*)&labk[cur][kg * 16 + quad * 4];
        bool m0 = !OUTSIDE || (lk4.x & 0x100), m1 = !OUTSIDE || (lk4.y & 0x100);
        bool m2 = !OUTSIDE || (lk4.z & 0x100), m3 = !OUTSIDE || (lk4.w & 0x100);
        int k0l = lk4.x & 0xff, k1l = lk4.y & 0xff, k2l = lk4.z & 0xff, k3l = lk4.w & 0xff;
        bf16x4 pf0, pf1;
        {
          float p0 = (k0l == lq0 && m0) ? __expf(sa0[0]) : 0.f;
          float p1 = (k1l == lq0 && m1) ? __expf(sa0[1]) : 0.f;
          float p2 = (k2l == lq0 && m2) ? __expf(sa0[2]) : 0.f;
          float p3 = (k3l == lq0 && m3) ? __expf(sa0[3]) : 0.f;
          lp0 += (p0 + p1) + (p2 + p3);
          pf0[0] = (short)f2bf(p0); pf0[1] = (short)f2bf(p1);
          pf0[2] = (short)f2bf(p2); pf0[3] = (short)f2bf(p3);
        }
        {
          float p0 = (k0l == lq1 && m0) ? __expf(sa1[0]) : 0.f;
          float p1 = (k1l == lq1 && m1) ? __expf(sa1[1]) : 0.f;
          float p2 = (k2l == lq1 && m2) ? __expf(sa1[2]) : 0.f;
          float p3 = (k3l == lq1 && m3) ? __expf(sa1[3]) : 0.f;
          lp1 += (p0 + p1) + (p2 + p3);
          pf1[0] = (short)f2bf(p0); pf1[1] = (short)f2bf(p1);
          pf1[2] = (short)f2bf(p2); pf1[3] = (short)f2bf(p3);
        }
        // O^T += V^T * P^T, two query sets share vf
        setprio<1>();
#pragma unroll
        for (int dt = 0; dt < 5; dt++){
          bf16x4 vf = *(const bf16x4*)&Vt[cur][(dt * 16 + l16) * VP + kg * 16 + quad * 4];
          Oc0[dt] = mfma16(vf, pf0, Oc0[dt]);
          Oc1[dt] = mfma16(vf, pf1, Oc1[dt]);
        }
        setprio<0>();
      }
      __syncthreads();   // all reads of cur done; writes of nxt visible
      cur = nxt;
    }
  }
#undef LOADT
#undef WRITET
  // row-sums: reduce across quads (same l16); write UNNORMALIZED partials
  lp0 += __shfl_xor(lp0, 16); lp0 += __shfl_xor(lp0, 32);
  lp1 += __shfl_xor(lp1, 16); lp1 += __shfl_xor(lp1, 32);
  int hz = third * 2 + bz;
  if (quad == 0){
    lpP[(size_t)(hz * 8 + h) * S_LEN + qrow0] = lp0;
    lpP[(size_t)(hz * 8 + h) * S_LEN + qrow1] = lp1;
  }
  unsigned short* dst = opart + (size_t)hz * S_LEN * CDIM;
#pragma unroll
  for (int dt = 0; dt < 5; dt++){
    ushort4 o;
    o.x = f2bf(Oc0[dt][0]); o.y = f2bf(Oc0[dt][1]);
    o.z = f2bf(Oc0[dt][2]); o.w = f2bf(Oc0[dt][3]);
    *(ushort4*)&dst[(size_t)qrow0 * CDIM + h * 80 + dt * 16 + quad * 4] = o;
    o.x = f2bf(Oc1[dt][0]); o.y = f2bf(Oc1[dt][1]);
    o.z = f2bf(Oc1[dt][2]); o.w = f2bf(Oc1[dt][3]);
    *(ushort4*)&dst[(size_t)qrow1 * CDIM + h * 80 + dt * 16 + quad * 4] = o;
  }
}

// ---------------- combine: planes[z] = sum of 3 partial O / sum of 3 partial lp
__global__ __launch_bounds__(256) void k_comb(const unsigned short* __restrict__ opart,
                                              const float* __restrict__ lpP,
                                              unsigned short* __restrict__ planes){
  int i = blockIdx.x * 256 + threadIdx.x;          // 4096*160 items per z
  int z = blockIdx.y;
  int qrow = i / 160, c4 = (i % 160) * 4;
  int h = c4 / 80;                                  // 80 % 4 == 0: one h per ushort4
  size_t base = (size_t)qrow * CDIM + c4;
  size_t pz = (size_t)S_LEN * CDIM;
  float lp = lpP[(size_t)((z)     * 8 + h) * S_LEN + qrow]
           + lpP[(size_t)((z + 2) * 8 + h) * S_LEN + qrow]
           + lpP[(size_t)((z + 4) * 8 + h) * S_LEN + qrow];
  float iL = 1.f / lp;
  ushort4 a = *(const ushort4*)&opart[(size_t)(z)     * pz + base];
  ushort4 b = *(const ushort4*)&opart[(size_t)(z + 2) * pz + base];
  ushort4 c = *(const ushort4*)&opart[(size_t)(z + 4) * pz + base];
  ushort4 o;
  o.x = f2bf((b2f(a.x) + b2f(b.x) + b2f(c.x)) * iL);
  o.y = f2bf((b2f(a.y) + b2f(b.y) + b2f(c.y)) * iL);
  o.z = f2bf((b2f(a.z) + b2f(b.z) + b2f(c.z)) * iL);
  o.w = f2bf((b2f(a.w) + b2f(b.w) + b2f(c.w)) * iL);
  *(ushort4*)&planes[(size_t)z * pz + base] = o;
}

// ---------------- entity E1: P = exp(Q_e K_e^T) per (qtile, ktile), bf16, + rowsums
// BK=64 staging; T1 XCD-chunked remap (consecutive k-tiles of one qt share
// the Q_e panel -> same XCD L2).
__global__ __launch_bounds__(256) void k_ent_qk(const unsigned short* __restrict__ proj,
                                                const int* __restrict__ labP,
                                                const int4* __restrict__ qtinfo,
                                                unsigned short* __restrict__ Sbuf,
                                                float* __restrict__ rowsum){
  int d = blockIdx.y * gridDim.x + blockIdx.x;
  int o = xcd_chunk(d, gridDim.x * gridDim.y);
  int ktb = o % gridDim.x, qt = o / gridDim.x;
  int4 qi = qtinfo[qt];
  int nkt = (qi.y - qi.x) >> 7;
  if (ktb >= nkt) return;
  int m0 = qt * 128, n0 = qi.x + ktb * 128;
  __shared__ __align__(16) unsigned short As[128 * 64];
  __shared__ __align__(16) unsigned short Bs[128 * 64];
  __shared__ int lQ[128], lK[128];
  int tid = threadIdx.x, wid = tid >> 6, lane = tid & 63;
  int quad = lane >> 4, l16 = lane & 15;
  int wm = (wid >> 1) * 64, wn = (wid & 1) * 64;
  if (tid < 128) lQ[tid] = labP[m0 + tid] & 0xff;
  else           lK[tid - 128] = labP[n0 + tid - 128] & 0xff;
  f32x4 acc[4][4];
#pragma unroll
  for (int i = 0; i < 4; i++)
#pragma unroll
    for (int j = 0; j < 4; j++) acc[i][j] = f32x4{0.f, 0.f, 0.f, 0.f};

  for (int k0 = 0; k0 < 640; k0 += 64){
    __syncthreads();
#pragma unroll
    for (int u = 0; u < 4; u++){
      int c = tid + u * 256;
      int row = c >> 3, off = (c & 7) * 8;
      gload_lds(&proj[(size_t)(m0 + row) * NPROJ + 1920 + k0 + off], &As[c * 8]);
      gload_lds(&proj[(size_t)(n0 + row) * NPROJ + 2560 + k0 + off], &Bs[c * 8]);
    }
    __syncthreads();
#pragma unroll
    for (int ks = 0; ks < 2; ks++){
      bf16x8 af[4], bfr[4];
#pragma unroll
      for (int t = 0; t < 4; t++){
        af[t]  = *(const bf16x8*)(&As[(wm + t * 16 + l16) * 64 + ks * 32 + quad * 8]);
        bfr[t] = *(const bf16x8*)(&Bs[(wn + t * 16 + l16) * 64 + ks * 32 + quad * 8]);
      }
#pragma unroll
      for (int mt = 0; mt < 4; mt++)
#pragma unroll
        for (int nt = 0; nt < 4; nt++)
          acc[mt][nt] = __builtin_amdgcn_mfma_f32_16x16x32_bf16(af[mt], bfr[nt], acc[mt][nt], 0, 0, 0);
    }
  }
  unsigned short* St = Sbuf + ((size_t)(qi.z + ktb)) * 16384;
#pragma unroll
  for (int mt = 0; mt < 4; mt++)
#pragma unroll
    for (int r = 0; r < 4; r++){
      int lrow = wm + mt * 16 + quad * 4 + r;
      int myq = lQ[lrow];
      float psum = 0.f;
#pragma unroll
      for (int nt = 0; nt < 4; nt++){
        int lcol = wn + nt * 16 + l16;
        float p = (myq == lK[lcol]) ? __expf(acc[mt][nt][r]) : 0.f;
        St[lrow * 128 + lcol] = f2bf(p);
        psum += p;
      }
#pragma unroll
      for (int m = 1; m < 16; m <<= 1) psum += __shfl_xor(psum, m);
      if (l16 == 0) atomicAdd(&rowsum[m0 + lrow], psum);
    }
}

// ---------------- entity E2: attnS = bf16( P·V_e / rowsum + plane0 + plane1 )
// BK=64; T1 XCD-chunked remap (the 5 d-blocks of one qt share its P buffer).
__global__ __launch_bounds__(256) void k_ent_pv(const unsigned short* __restrict__ Sbuf,
                                                const unsigned short* __restrict__ veT,
                                                const int4* __restrict__ qtinfo,
                                                const float* __restrict__ rowsum,
                                                const unsigned short* __restrict__ planes,
                                                unsigned short* __restrict__ attnS){
  int d = blockIdx.y * gridDim.x + blockIdx.x;
  int o = xcd_chunk(d, gridDim.x * gridDim.y);
  int qt = o / gridDim.x, d0 = (o % gridDim.x) * 128;
  int4 qi = qtinfo[qt];
  int m0 = qt * 128;
  int nk = qi.y - qi.x;
  __shared__ __align__(16) unsigned short As[128 * 64];
  __shared__ __align__(16) unsigned short Bs[128 * 64];
  int tid = threadIdx.x, wid = tid >> 6, lane = tid & 63;
  int quad = lane >> 4, l16 = lane & 15;
  int wm = (wid >> 1) * 64, wn = (wid & 1) * 64;
  f32x4 acc[4][4];
#pragma unroll
  for (int i = 0; i < 4; i++)
#pragma unroll
    for (int j = 0; j < 4; j++) acc[i][j] = f32x4{0.f, 0.f, 0.f, 0.f};

  for (int kk = 0; kk < nk; kk += 64){
    const unsigned short* St = Sbuf + ((size_t)(qi.z + (kk >> 7))) * 16384;
    int kloc = kk & 127;
    __syncthreads();
#pragma unroll
    for (int u = 0; u < 4; u++){
      int c = tid + u * 256;
      int row = c >> 3, off = (c & 7) * 8;
      gload_lds(&St[row * 128 + kloc + off], &As[c * 8]);
      gload_lds(&veT[(size_t)(d0 + row) * S_LEN + qi.x + kk + off], &Bs[c * 8]);
    }
    __syncthreads();
#pragma unroll
    for (int ks = 0; ks < 2; ks++){
      bf16x8 af[4], bfr[4];
#pragma unroll
      for (int t = 0; t < 4; t++){
        af[t]  = *(const bf16x8*)(&As[(wm + t * 16 + l16) * 64 + ks * 32 + quad * 8]);
        bfr[t] = *(const bf16x8*)(&Bs[(wn + t * 16 + l16) * 64 + ks * 32 + quad * 8]);
      }
#pragma unroll
      for (int mt = 0; mt < 4; mt++)
#pragma unroll
        for (int nt = 0; nt < 4; nt++)
          acc[mt][nt] = __builtin_amdgcn_mfma_f32_16x16x32_bf16(af[mt], bfr[nt], acc[mt][nt], 0, 0, 0);
    }
  }
#pragma unroll
  for (int mt = 0; mt < 4; mt++)
#pragma unroll
    for (int r = 0; r < 4; r++){
      int row = m0 + wm + mt * 16 + quad * 4 + r;
      float invL = 1.f / rowsum[row];
#pragma unroll
      for (int nt = 0; nt < 4; nt++){
        int col = d0 + wn + nt * 16 + l16;
        size_t idx = (size_t)row * CDIM + col;
        float v = acc[mt][nt][r] * invL + b2f(planes[idx]) + b2f(planes[(size_t)S_LEN * CDIM + idx]);
        attnS[idx] = f2bf(v);
      }
    }
}

extern "C" void kernel_launch(void* const* d_in, const int* in_sizes, int n_in,
                              void* d_out, int out_size, void* d_ws, size_t ws_size,
                              hipStream_t stream){
  const float* hs  = (const float*)d_in[0];
  const int* mask  = (const int*)d_in[1];
  const int* inp   = (const int*)d_in[2];
  char* ws = (char*)d_ws;
  int*            labels  = (int*)(ws + 0);
  int*            perm    = (int*)(ws + 16896);
  int*            inv     = (int*)(ws + 33280);
  int*            labP    = (int*)(ws + 49664);
  int4*           qtinfo  = (int4*)(ws + 66560);
  float*          rowsum  = (float*)(ws + 67072);
  unsigned short* hsb     = (unsigned short*)(ws + 131072);
  unsigned short* Wall    = (unsigned short*)(ws + 5373952);
  unsigned short* proj    = (unsigned short*)(ws + 13565952);
  unsigned short* vT      = (unsigned short*)(ws + 60751872);
  unsigned short* planes  = (unsigned short*)(ws + 76480512);   // 2 bf16 planes = 10.5 MB
  unsigned short* Sbuf    = (unsigned short*)(ws + 86966272);   // up to 1024 tiles * 32 KB
  unsigned short* attnS   = (unsigned short*)(ws + 120520704);
  unsigned short* Wob     = Wall + 9 * 409600;
  // attn partials live in the Sbuf region (consumed by k_comb BEFORE k_ent_qk
  // overwrites Sbuf): opart = 6 x [4096][640] bf16 (31.5 MB), lpP = 6x8x4096 f32.
  unsigned short* opart   = Sbuf;
  float*          lpP     = (float*)(ws + 86966272 + 31457280);

  k_prep<<<1, 1024, 0, stream>>>(mask, inp, labels, perm, inv, labP, qtinfo, rowsum);
  WPtrs wp;
  for (int i = 0; i < 10; i++) wp.w[i] = (const float*)d_in[3 + i];
  k_cvt_all<<<2560 + 4000, 256, 0, stream>>>(hs, wp, hsb, Wall);

  // all 9 projections in one GEMM, rows scattered into bucket-permuted order
  k_gemm<0><<<dim3(45, 32), 256, 0, stream>>>(hsb, Wall, S_LEN, NPROJ, CDIM, NPROJ,
                                              inv, proj, nullptr, nullptr);
  k_transpose_v<<<dim3(64, 10, 3), 256, 0, stream>>>(proj, vT);

  // branches 1+3: 256-query 8-wave blocks + 3-way key split; partials + combine
  k_attn80<<<dim3(48, 8, 2), 512, 0, stream>>>(proj, vT, labP, qtinfo, opart, lpP);
  k_comb<<<dim3(2560, 2), 256, 0, stream>>>(opart, lpP, planes);

  // branch 2 (entity, d=640): GEMM-ified, P materialized bf16 per bucket
  k_ent_qk<<<dim3(32, 32), 256, 0, stream>>>(proj, labP, qtinfo, Sbuf, rowsum);
  k_ent_pv<<<dim3(5, 32), 256, 0, stream>>>(Sbuf, vT + (size_t)1 * CDIM * S_LEN,
                                            qtinfo, rowsum, planes, attnS);

  // out = attnS @ Wo^T + residual, un-permuted via perm in the epilogue
  k_gemm<1><<<dim3(5, 32), 256, 0, stream>>>(attnS, Wob, S_LEN, CDIM, CDIM, CDIM,
                                             perm, nullptr, (float*)d_out, hs);
}

// Round 16
// 345.341 us; speedup vs baseline: 1.0173x; 1.0173x over previous
//
#include <hip/hip_runtime.h>
#include <cstdint>

typedef __attribute__((ext_vector_type(8))) short bf16x8;
typedef __attribute__((ext_vector_type(4))) short bf16x4;
typedef __attribute__((ext_vector_type(4))) float f32x4;

#define S_LEN 4096
#define CDIM  640
#define NPROJ 5760

// K=16 bf16 MFMA (v_mfma_f32_16x16x16_bf16, gfx950-valid per ISA §10).
__device__ __forceinline__ f32x4 mfma16(bf16x4 a, bf16x4 b, f32x4 c){
#if defined(__HIP_DEVICE_COMPILE__) && __HIP_DEVICE_COMPILE__
  return __builtin_amdgcn_mfma_f32_16x16x16bf16_1k(a, b, c, 0, 0, 0);
#else
  (void)a; (void)b;
  return c;
#endif
}

// async global->LDS, 16B per lane; LDS dest must be wave-uniform base + lane*16
__device__ __forceinline__ void gload_lds(const unsigned short* g, unsigned short* l){
#if defined(__HIP_DEVICE_COMPILE__) && __HIP_DEVICE_COMPILE__
  __builtin_amdgcn_global_load_lds((const __attribute__((address_space(1))) unsigned int*)g,
                                   (__attribute__((address_space(3))) unsigned int*)l, 16, 0, 0);
#else
  (void)g; (void)l;
#endif
}

__device__ __forceinline__ unsigned short f2bf(float f){
  union { float f; uint32_t u; } v; v.f = f;
  uint32_t u = v.u;
  return (unsigned short)((u + 0x7fffu + ((u >> 16) & 1u)) >> 16);
}
__device__ __forceinline__ float b2f(unsigned short h){
  union { uint32_t u; float f; } v; v.u = ((uint32_t)h) << 16;
  return v.f;
}

// T1 XCD-chunked remap: HW assigns dispatch index d to XCD d%8 round-robin;
// remap so each XCD executes a CONTIGUOUS chunk of original tile ids
// (L2 reuse of shared operand panels). Requires nwg % 8 == 0 (all our grids).
__device__ __forceinline__ int xcd_chunk(int d, int nwg){
  return (d & 7) * (nwg >> 3) + (d >> 3);
}

// ---------------- R21: fused prologue (was k_labels/k_hist/k_perm/k_tiles).
__global__ __launch_bounds__(1024) void k_prep(const int* __restrict__ mask,
                                               const int* __restrict__ inp,
                                               int* __restrict__ labels,
                                               int* __restrict__ perm,
                                               int* __restrict__ inv,
                                               int* __restrict__ labP,
                                               int4* __restrict__ qtinfo,
                                               float* __restrict__ rowsum){
  __shared__ int h[4], base[5], cnt4[4], nkt[32];
  int t = threadIdx.x;
  if (t < 4){ h[t] = 0; cnt4[t] = 0; }
  __syncthreads();
  // labels + histogram
  for (int s = t; s < S_LEN; s += 1024){
    int y = s >> 6, x = s & 63;
    int off = (y * 8) * 512 + x * 8;
    int m = mask[off] & 0xff;
    int o = (inp[off] == 0) ? 0x100 : 0;
    labels[s] = m | o;
    atomicAdd(&h[m & 3], 1);
  }
  __syncthreads();
  if (t == 0){
    int a = 0;
    for (int c = 0; c < 4; c++){ base[c] = a; a += h[c]; }
    base[4] = a;
  }
  __syncthreads();
  // bucket-sort permutation (arrival order within bucket, same as before)
  for (int s = t; s < S_LEN; s += 1024){
    int lab = labels[s];
    int c = lab & 3;
    int pos = base[c] + atomicAdd(&cnt4[c], 1);
    perm[pos] = s; inv[s] = pos; labP[pos] = lab;
  }
  __syncthreads();   // labP globally visible within block
  // per-128-tile key ranges
  if (t < 32){
    int c0 = labP[t * 128] & 3, c1 = labP[t * 128 + 127] & 3;
    int lo = base[c0] & ~127, hi = (base[c1 + 1] + 127) & ~127;
    qtinfo[t].x = lo; qtinfo[t].y = hi; qtinfo[t].w = 0;
    nkt[t] = (hi - lo) >> 7;
  }
  __syncthreads();
  if (t == 0){
    int a = 0;
    for (int i = 0; i < 32; i++){ qtinfo[i].z = a; a += nkt[i]; }
  }
  for (int s = t; s < S_LEN; s += 1024) rowsum[s] = 0.f;
}

// ---------------- fused f32 -> bf16 converts (hs + weights, one launch)
struct WPtrs { const float* w[10]; };

__global__ void k_cvt_all(const float* __restrict__ hs, WPtrs p,
                          unsigned short* __restrict__ hsb,
                          unsigned short* __restrict__ wall){
  int b = blockIdx.x;
  if (b < 2560){
    int idx = (b * 256 + threadIdx.x) * 4;          // 4096*640 exactly
    float4 v = *(const float4*)(hs + idx);
    ushort4 o;
    o.x = f2bf(v.x); o.y = f2bf(v.y); o.z = f2bf(v.z); o.w = f2bf(v.w);
    *(ushort4*)(hsb + idx) = o;
  } else {
    int e = ((b - 2560) * 256 + threadIdx.x) * 4;   // 10*409600 exactly
    int a = e / 409600, r = e % 409600;
    float sc = (a == 0 || a == 6) ? 0.11180339887498948f   // 1/sqrt(80)
             : (a == 3 ? 0.03952847075210474f : 1.0f);     // 1/sqrt(640)
    float4 v = *(const float4*)(p.w[a] + r);
    ushort4 o;
    o.x = f2bf(v.x * sc); o.y = f2bf(v.y * sc); o.z = f2bf(v.z * sc); o.w = f2bf(v.w * sc);
    *(ushort4*)(wall + e) = o;
  }
}

// ---------------- 128x128 MFMA GEMM
// BK=64, pitch-64 LDS, gload_lds staging. T1 XCD-chunked tile remap --
// consecutive tiles (sharing the A row-panel) land on the same XCD's L2.
template<int EPI>
__global__ __launch_bounds__(256) void k_gemm(const unsigned short* __restrict__ A,
                                              const unsigned short* __restrict__ B,
                                              int M, int N, int K, int ldc,
                                              const int* __restrict__ rowmap,
                                              unsigned short* __restrict__ Cb,
                                              float* __restrict__ Cf,
                                              const float* __restrict__ resid){
  __shared__ __align__(16) unsigned short As[128 * 64];
  __shared__ __align__(16) unsigned short Bs[128 * 64];
  int d = blockIdx.y * gridDim.x + blockIdx.x;
  int o = xcd_chunk(d, gridDim.x * gridDim.y);
  int m0 = (o / gridDim.x) * 128, n0 = (o % gridDim.x) * 128;
  int tid = threadIdx.x;
  int wid = tid >> 6, lane = tid & 63;
  int quad = lane >> 4, l16 = lane & 15;
  int wm = (wid >> 1) * 64, wn = (wid & 1) * 64;
  f32x4 acc[4][4];
#pragma unroll
  for (int i = 0; i < 4; i++)
#pragma unroll
    for (int j = 0; j < 4; j++) acc[i][j] = f32x4{0.f, 0.f, 0.f, 0.f};

  for (int k0 = 0; k0 < K; k0 += 64){
    __syncthreads();
#pragma unroll
    for (int u = 0; u < 4; u++){
      int c = tid + u * 256;
      int row = c >> 3, off = (c & 7) * 8;
      gload_lds(&A[(size_t)(m0 + row) * K + k0 + off], &As[c * 8]);
      gload_lds(&B[(size_t)(n0 + row) * K + k0 + off], &Bs[c * 8]);
    }
    __syncthreads();
#pragma unroll
    for (int ks = 0; ks < 2; ks++){
      bf16x8 af[4], bfr[4];
#pragma unroll
      for (int t = 0; t < 4; t++){
        af[t]  = *(const bf16x8*)(&As[(wm + t * 16 + l16) * 64 + ks * 32 + quad * 8]);
        bfr[t] = *(const bf16x8*)(&Bs[(wn + t * 16 + l16) * 64 + ks * 32 + quad * 8]);
      }
#pragma unroll
      for (int mt = 0; mt < 4; mt++)
#pragma unroll
        for (int nt = 0; nt < 4; nt++)
          acc[mt][nt] = __builtin_amdgcn_mfma_f32_16x16x32_bf16(af[mt], bfr[nt], acc[mt][nt], 0, 0, 0);
    }
  }
#pragma unroll
  for (int mt = 0; mt < 4; mt++)
#pragma unroll
    for (int nt = 0; nt < 4; nt++)
#pragma unroll
      for (int r = 0; r < 4; r++){
        int row = m0 + wm + mt * 16 + quad * 4 + r;
        int col = n0 + wn + nt * 16 + l16;
        float v = acc[mt][nt][r];
        if (EPI == 0){
          Cb[(size_t)rowmap[row] * ldc + col] = f2bf(v);
        } else {
          int ro = rowmap[row];
          Cf[(size_t)ro * ldc + col] = v + resid[(size_t)ro * ldc + col];
        }
      }
}

// ---------------- transpose the three V projections: vT[z][c][s]
// uint2-vectorized both sides (R21). Streaming, no inter-block reuse -> no swizzle.
__global__ void k_transpose_v(const unsigned short* __restrict__ proj, unsigned short* __restrict__ vT){
  __shared__ unsigned short T[64][68];
  int z = blockIdx.z;
  int s0 = blockIdx.x * 64, c0 = blockIdx.y * 64;
  int colbase = 1280 + z * 1920 + c0;   // v:1280  v_e:3200  v_o:5120
  unsigned short* dst = vT + (size_t)z * CDIM * S_LEN;
  int tid = threadIdx.x;
#pragma unroll
  for (int u = 0; u < 4; u++){
    int i = tid + u * 256;               // 1024 uint2 units: r = i>>4, c4 = (i&15)*4
    int r = i >> 4, c4 = (i & 15) * 4;
    uint2 v = *(const uint2*)&proj[(size_t)(s0 + r) * NPROJ + colbase + c4];
    *(uint2*)&T[r][c4] = v;
  }
  __syncthreads();
#pragma unroll
  for (int u = 0; u < 4; u++){
    int j = tid + u * 256;               // c = j>>4, r4 = (j&15)*4
    int c = j >> 4, r4 = (j & 15) * 4;
    ushort4 o;
    o.x = T[r4 + 0][c]; o.y = T[r4 + 1][c];
    o.z = T[r4 + 2][c]; o.w = T[r4 + 3][c];
    *(ushort4*)&dst[(size_t)(c0 + c) * S_LEN + s0 + r4] = o;
  }
}

// ---------------- flash attention, d=80, z=0: orig, z=1: outside
// R23 config (best known: 92.1 us): 3-way key split, 256-query 8-wave blocks,
// waves 0-3 stage K / 4-7 stage V, T1 XCD remap. NO setprio: R25 showed it
// perturbs codegen (VGPR 88->68, LDS conflicts 252K->2.27M, +5.4 us).
#define KP 84
#define VP 76
__global__ __launch_bounds__(512, 2) void k_attn80(const unsigned short* __restrict__ proj,
                                                   const unsigned short* __restrict__ vT,
                                                   const int* __restrict__ labP,
                                                   const int4* __restrict__ qtinfo,
                                                   unsigned short* __restrict__ opart,
                                                   float* __restrict__ lpP){
  __shared__ __align__(16) unsigned short Ks[2][64 * KP];
  __shared__ __align__(16) unsigned short Vt[2][80 * VP];
  __shared__ __align__(16) int labk[2][64];
  int tid = threadIdx.x, wid = tid >> 6, lane = tid & 63;
  int quad = lane >> 4, l16 = lane & 15;
  // T1 remap over the flattened grid (x fastest in dispatch order)
  int d = (int)(blockIdx.z * gridDim.y + blockIdx.y) * gridDim.x + blockIdx.x;
  int og = xcd_chunk(d, (int)(gridDim.x * gridDim.y * gridDim.z));
  int bx = og % gridDim.x;
  int by = (og / gridDim.x) % gridDim.y;
  int bz = og / (gridDim.x * gridDim.y);
  int qt = bx / 3, third = bx % 3;
  int q0 = qt * 256;
  int h  = by;
  bool OUTSIDE = (bz == 1);
  int qc = (OUTSIDE ? 3840 : 0) + h * 80;
  int kc = (OUTSIDE ? 4480 : 640) + h * 80;
  const unsigned short* vTb = vT + (size_t)(OUTSIDE ? 2 : 0) * CDIM * S_LEN;
  int4 qa = qtinfo[qt * 2], qb = qtinfo[qt * 2 + 1];
  int lo = min(qa.x, qb.x), hi = max(qa.y, qb.y);
  int t0 = lo >> 6, t1 = hi >> 6;
  int nt = t1 - t0;
  int ta = t0 + (nt * third) / 3;
  int tb = t0 + (nt * (third + 1)) / 3;

  // two query sets per wave (B-operand layout: lane n=l16 is the query, k=quad*4+j)
  int qrow0 = q0 + wid * 32 + l16;
  int qrow1 = qrow0 + 16;
  bf16x4 qf0[5], qf1[5];
#pragma unroll
  for (int dc = 0; dc < 5; dc++){
    qf0[dc] = *(const bf16x4*)&proj[(size_t)qrow0 * NPROJ + qc + dc * 16 + quad * 4];
    qf1[dc] = *(const bf16x4*)&proj[(size_t)qrow1 * NPROJ + qc + dc * 16 + quad * 4];
  }
  int lq0 = labP[qrow0] & 0xff, lq1 = labP[qrow1] & 0xff;

  float lp0 = 0.f, lp1 = 0.f;
  f32x4 Oc0[5], Oc1[5];
#pragma unroll
  for (int t = 0; t < 5; t++){ Oc0[t] = f32x4{0.f,0.f,0.f,0.f}; Oc1[t] = f32x4{0.f,0.f,0.f,0.f}; }

  // staging roles: waves 0-3 stage the K tile (64 rows x 20 uint2), waves 4-7
  // stage the V tile (80 rows x 16 uint2). 1280 uint2 per role over 256
  // threads = 5 units/thread; unit c = t5 + u*256. All tile-invariant.
  const bool ISK = (tid < 256);
  const int t5 = ISK ? tid : (tid - 256);
  const unsigned short* gb = ISK ? proj : vTb;
  const int km = ISK ? NPROJ : 1;                    // per-tile offset multiplier
  int ga0, ga1, ga2, ga3, ga4, ls0, ls1, ls2, ls3, ls4;
  {
    const int c0_ = t5, c1_ = t5 + 256, c2_ = t5 + 512, c3_ = t5 + 768, c4_ = t5 + 1024;
    if (ISK){
      ga0 = (c0_ / 20) * NPROJ + kc + (c0_ % 20) * 4;
      ga1 = (c1_ / 20) * NPROJ + kc + (c1_ % 20) * 4;
      ga2 = (c2_ / 20) * NPROJ + kc + (c2_ % 20) * 4;
      ga3 = (c3_ / 20) * NPROJ + kc + (c3_ % 20) * 4;
      ga4 = (c4_ / 20) * NPROJ + kc + (c4_ % 20) * 4;
      ls0 = (c0_ / 20) * KP + (c0_ % 20) * 4;
      ls1 = (c1_ / 20) * KP + (c1_ % 20) * 4;
      ls2 = (c2_ / 20) * KP + (c2_ % 20) * 4;
      ls3 = (c3_ / 20) * KP + (c3_ % 20) * 4;
      ls4 = (c4_ / 20) * KP + (c4_ % 20) * 4;
    } else {
      ga0 = (h * 80 + (c0_ >> 4)) * S_LEN + (c0_ & 15) * 4;
      ga1 = (h * 80 + (c1_ >> 4)) * S_LEN + (c1_ & 15) * 4;
      ga2 = (h * 80 + (c2_ >> 4)) * S_LEN + (c2_ & 15) * 4;
      ga3 = (h * 80 + (c3_ >> 4)) * S_LEN + (c3_ & 15) * 4;
      ga4 = (h * 80 + (c4_ >> 4)) * S_LEN + (c4_ & 15) * 4;
      ls0 = (c0_ >> 4) * VP + (c0_ & 15) * 4;
      ls1 = (c1_ >> 4) * VP + (c1_ & 15) * 4;
      ls2 = (c2_ >> 4) * VP + (c2_ & 15) * 4;
      ls3 = (c3_ >> 4) * VP + (c3_ & 15) * 4;
      ls4 = (c4_ >> 4) * VP + (c4_ & 15) * 4;
    }
  }

  uint2 r0, r1, r2, r3, r4;
  int lreg = 0;

#define LOADT(kt_) do {                                              \
    size_t _ob = (size_t)((kt_) * 64) * (size_t)km;                  \
    r0 = *(const uint2*)&gb[_ob + ga0];                              \
    r1 = *(const uint2*)&gb[_ob + ga1];                              \
    r2 = *(const uint2*)&gb[_ob + ga2];                              \
    r3 = *(const uint2*)&gb[_ob + ga3];                              \
    r4 = *(const uint2*)&gb[_ob + ga4];                              \
    if (tid < 64) lreg = labP[(kt_) * 64 + tid];                     \
  } while (0)

#define WRITET(b) do {                                               \
    unsigned short* _lb = ISK ? Ks[b] : Vt[b];                       \
    *(uint2*)&_lb[ls0] = r0;                                         \
    *(uint2*)&_lb[ls1] = r1;                                         \
    *(uint2*)&_lb[ls2] = r2;                                         \
    *(uint2*)&_lb[ls3] = r3;                                         \
    *(uint2*)&_lb[ls4] = r4;                                         \
    if (tid < 64) labk[b][tid] = lreg;                               \
  } while (0)

  if (ta < tb){
    // prologue: stage tile ta into buf0, issue loads for ta+1
    LOADT(ta);
    WRITET(0);
    if (ta + 1 < tb) LOADT(ta + 1);
    __syncthreads();

    int cur = 0;
    for (int kt = ta; kt < tb; kt++){
      int nxt = cur ^ 1;
      // regs hold tile kt+1: write it to the other buffer (its readers finished
      // at the barrier that ended iteration kt-1), then issue loads for kt+2.
      if (kt + 1 < tb){
        WRITET(nxt);
        if (kt + 2 < tb) LOADT(kt + 2);
      }

#pragma unroll
      for (int kg = 0; kg < 4; kg++){
        // S^T(16 keys x 16 queries) = K * Q^T, two query sets share kf
        f32x4 sa0 = f32x4{0.f,0.f,0.f,0.f}, sa1 = f32x4{0.f,0.f,0.f,0.f};
#pragma unroll
        for (int dc = 0; dc < 5; dc++){
          bf16x4 kf = *(const bf16x4*)&Ks[cur][(kg * 16 + l16) * KP + dc * 16 + quad * 4];
          sa0 = mfma16(kf, qf0[dc], sa0);
          sa1 = mfma16(kf, qf1[dc], sa1);
        }
        int4 lk4 = *(const int4*)&labk[cur][kg * 16 + quad * 4];
        bool m0 = !OUTSIDE || (lk4.x & 0x100), m1 = !OUTSIDE || (lk4.y & 0x100);
        bool m2 = !OUTSIDE || (lk4.z & 0x100), m3 = !OUTSIDE || (lk4.w & 0x100);
        int k0l = lk4.x & 0xff, k1l = lk4.y & 0xff, k2l = lk4.z & 0xff, k3l = lk4.w & 0xff;
        bf16x4 pf0, pf1;
        {
          float p0 = (k0l == lq0 && m0) ? __expf(sa0[0]) : 0.f;
          float p1 = (k1l == lq0 && m1) ? __expf(sa0[1]) : 0.f;
          float p2 = (k2l == lq0 && m2) ? __expf(sa0[2]) : 0.f;
          float p3 = (k3l == lq0 && m3) ? __expf(sa0[3]) : 0.f;
          lp0 += (p0 + p1) + (p2 + p3);
          pf0[0] = (short)f2bf(p0); pf0[1] = (short)f2bf(p1);
          pf0[2] = (short)f2bf(p2); pf0[3] = (short)f2bf(p3);
        }
        {
          float p0 = (k0l == lq1 && m0) ? __expf(sa1[0]) : 0.f;
          float p1 = (k1l == lq1 && m1) ? __expf(sa1[1]) : 0.f;
          float p2 = (k2l == lq1 && m2) ? __expf(sa1[2]) : 0.f;
          float p3 = (k3l == lq1 && m3) ? __expf(sa1[3]) : 0.f;
          lp1 += (p0 + p1) + (p2 + p3);
          pf1[0] = (short)f2bf(p0); pf1[1] = (short)f2bf(p1);
          pf1[2] = (short)f2bf(p2); pf1[3] = (short)f2bf(p3);
        }
        // O^T += V^T * P^T, two query sets share vf
#pragma unroll
        for (int dt = 0; dt < 5; dt++){
          bf16x4 vf = *(const bf16x4*)&Vt[cur][(dt * 16 + l16) * VP + kg * 16 + quad * 4];
          Oc0[dt] = mfma16(vf, pf0, Oc0[dt]);
          Oc1[dt] = mfma16(vf, pf1, Oc1[dt]);
        }
      }
      __syncthreads();   // all reads of cur done; writes of nxt visible
      cur = nxt;
    }
  }
#undef LOADT
#undef WRITET
  // row-sums: reduce across quads (same l16); write UNNORMALIZED partials
  lp0 += __shfl_xor(lp0, 16); lp0 += __shfl_xor(lp0, 32);
  lp1 += __shfl_xor(lp1, 16); lp1 += __shfl_xor(lp1, 32);
  int hz = third * 2 + bz;
  if (quad == 0){
    lpP[(size_t)(hz * 8 + h) * S_LEN + qrow0] = lp0;
    lpP[(size_t)(hz * 8 + h) * S_LEN + qrow1] = lp1;
  }
  unsigned short* dst = opart + (size_t)hz * S_LEN * CDIM;
#pragma unroll
  for (int dt = 0; dt < 5; dt++){
    ushort4 o;
    o.x = f2bf(Oc0[dt][0]); o.y = f2bf(Oc0[dt][1]);
    o.z = f2bf(Oc0[dt][2]); o.w = f2bf(Oc0[dt][3]);
    *(ushort4*)&dst[(size_t)qrow0 * CDIM + h * 80 + dt * 16 + quad * 4] = o;
    o.x = f2bf(Oc1[dt][0]); o.y = f2bf(Oc1[dt][1]);
    o.z = f2bf(Oc1[dt][2]); o.w = f2bf(Oc1[dt][3]);
    *(ushort4*)&dst[(size_t)qrow1 * CDIM + h * 80 + dt * 16 + quad * 4] = o;
  }
}

// ---------------- combine: planes[z] = sum of 3 partial O / sum of 3 partial lp
__global__ __launch_bounds__(256) void k_comb(const unsigned short* __restrict__ opart,
                                              const float* __restrict__ lpP,
                                              unsigned short* __restrict__ planes){
  int i = blockIdx.x * 256 + threadIdx.x;          // 4096*160 items per z
  int z = blockIdx.y;
  int qrow = i / 160, c4 = (i % 160) * 4;
  int h = c4 / 80;                                  // 80 % 4 == 0: one h per ushort4
  size_t base = (size_t)qrow * CDIM + c4;
  size_t pz = (size_t)S_LEN * CDIM;
  float lp = lpP[(size_t)((z)     * 8 + h) * S_LEN + qrow]
           + lpP[(size_t)((z + 2) * 8 + h) * S_LEN + qrow]
           + lpP[(size_t)((z + 4) * 8 + h) * S_LEN + qrow];
  float iL = 1.f / lp;
  ushort4 a = *(const ushort4*)&opart[(size_t)(z)     * pz + base];
  ushort4 b = *(const ushort4*)&opart[(size_t)(z + 2) * pz + base];
  ushort4 c = *(const ushort4*)&opart[(size_t)(z + 4) * pz + base];
  ushort4 o;
  o.x = f2bf((b2f(a.x) + b2f(b.x) + b2f(c.x)) * iL);
  o.y = f2bf((b2f(a.y) + b2f(b.y) + b2f(c.y)) * iL);
  o.z = f2bf((b2f(a.z) + b2f(b.z) + b2f(c.z)) * iL);
  o.w = f2bf((b2f(a.w) + b2f(b.w) + b2f(c.w)) * iL);
  *(ushort4*)&planes[(size_t)z * pz + base] = o;
}

// ---------------- entity E1: P = exp(Q_e K_e^T) per (qtile, ktile), bf16, + rowsums
// BK=64 staging; T1 XCD-chunked remap (consecutive k-tiles of one qt share
// the Q_e panel -> same XCD L2).
__global__ __launch_bounds__(256) void k_ent_qk(const unsigned short* __restrict__ proj,
                                                const int* __restrict__ labP,
                                                const int4* __restrict__ qtinfo,
                                                unsigned short* __restrict__ Sbuf,
                                                float* __restrict__ rowsum){
  int d = blockIdx.y * gridDim.x + blockIdx.x;
  int o = xcd_chunk(d, gridDim.x * gridDim.y);
  int ktb = o % gridDim.x, qt = o / gridDim.x;
  int4 qi = qtinfo[qt];
  int nkt = (qi.y - qi.x) >> 7;
  if (ktb >= nkt) return;
  int m0 = qt * 128, n0 = qi.x + ktb * 128;
  __shared__ __align__(16) unsigned short As[128 * 64];
  __shared__ __align__(16) unsigned short Bs[128 * 64];
  __shared__ int lQ[128], lK[128];
  int tid = threadIdx.x, wid = tid >> 6, lane = tid & 63;
  int quad = lane >> 4, l16 = lane & 15;
  int wm = (wid >> 1) * 64, wn = (wid & 1) * 64;
  if (tid < 128) lQ[tid] = labP[m0 + tid] & 0xff;
  else           lK[tid - 128] = labP[n0 + tid - 128] & 0xff;
  f32x4 acc[4][4];
#pragma unroll
  for (int i = 0; i < 4; i++)
#pragma unroll
    for (int j = 0; j < 4; j++) acc[i][j] = f32x4{0.f, 0.f, 0.f, 0.f};

  for (int k0 = 0; k0 < 640; k0 += 64){
    __syncthreads();
#pragma unroll
    for (int u = 0; u < 4; u++){
      int c = tid + u * 256;
      int row = c >> 3, off = (c & 7) * 8;
      gload_lds(&proj[(size_t)(m0 + row) * NPROJ + 1920 + k0 + off], &As[c * 8]);
      gload_lds(&proj[(size_t)(n0 + row) * NPROJ + 2560 + k0 + off], &Bs[c * 8]);
    }
    __syncthreads();
#pragma unroll
    for (int ks = 0; ks < 2; ks++){
      bf16x8 af[4], bfr[4];
#pragma unroll
      for (int t = 0; t < 4; t++){
        af[t]  = *(const bf16x8*)(&As[(wm + t * 16 + l16) * 64 + ks * 32 + quad * 8]);
        bfr[t] = *(const bf16x8*)(&Bs[(wn + t * 16 + l16) * 64 + ks * 32 + quad * 8]);
      }
#pragma unroll
      for (int mt = 0; mt < 4; mt++)
#pragma unroll
        for (int nt = 0; nt < 4; nt++)
          acc[mt][nt] = __builtin_amdgcn_mfma_f32_16x16x32_bf16(af[mt], bfr[nt], acc[mt][nt], 0, 0, 0);
    }
  }
  unsigned short* St = Sbuf + ((size_t)(qi.z + ktb)) * 16384;
#pragma unroll
  for (int mt = 0; mt < 4; mt++)
#pragma unroll
    for (int r = 0; r < 4; r++){
      int lrow = wm + mt * 16 + quad * 4 + r;
      int myq = lQ[lrow];
      float psum = 0.f;
#pragma unroll
      for (int nt = 0; nt < 4; nt++){
        int lcol = wn + nt * 16 + l16;
        float p = (myq == lK[lcol]) ? __expf(acc[mt][nt][r]) : 0.f;
        St[lrow * 128 + lcol] = f2bf(p);
        psum += p;
      }
#pragma unroll
      for (int m = 1; m < 16; m <<= 1) psum += __shfl_xor(psum, m);
      if (l16 == 0) atomicAdd(&rowsum[m0 + lrow], psum);
    }
}

// ---------------- entity E2: attnS = bf16( P·V_e / rowsum + plane0 + plane1 )
// BK=64; T1 XCD-chunked remap (the 5 d-blocks of one qt share its P buffer).
__global__ __launch_bounds__(256) void k_ent_pv(const unsigned short* __restrict__ Sbuf,
                                                const unsigned short* __restrict__ veT,
                                                const int4* __restrict__ qtinfo,
                                                const float* __restrict__ rowsum,
                                                const unsigned short* __restrict__ planes,
                                                unsigned short* __restrict__ attnS){
  int d = blockIdx.y * gridDim.x + blockIdx.x;
  int o = xcd_chunk(d, gridDim.x * gridDim.y);
  int qt = o / gridDim.x, d0 = (o % gridDim.x) * 128;
  int4 qi = qtinfo[qt];
  int m0 = qt * 128;
  int nk = qi.y - qi.x;
  __shared__ __align__(16) unsigned short As[128 * 64];
  __shared__ __align__(16) unsigned short Bs[128 * 64];
  int tid = threadIdx.x, wid = tid >> 6, lane = tid & 63;
  int quad = lane >> 4, l16 = lane & 15;
  int wm = (wid >> 1) * 64, wn = (wid & 1) * 64;
  f32x4 acc[4][4];
#pragma unroll
  for (int i = 0; i < 4; i++)
#pragma unroll
    for (int j = 0; j < 4; j++) acc[i][j] = f32x4{0.f, 0.f, 0.f, 0.f};

  for (int kk = 0; kk < nk; kk += 64){
    const unsigned short* St = Sbuf + ((size_t)(qi.z + (kk >> 7))) * 16384;
    int kloc = kk & 127;
    __syncthreads();
#pragma unroll
    for (int u = 0; u < 4; u++){
      int c = tid + u * 256;
      int row = c >> 3, off = (c & 7) * 8;
      gload_lds(&St[row * 128 + kloc + off], &As[c * 8]);
      gload_lds(&veT[(size_t)(d0 + row) * S_LEN + qi.x + kk + off], &Bs[c * 8]);
    }
    __syncthreads();
#pragma unroll
    for (int ks = 0; ks < 2; ks++){
      bf16x8 af[4], bfr[4];
#pragma unroll
      for (int t = 0; t < 4; t++){
        af[t]  = *(const bf16x8*)(&As[(wm + t * 16 + l16) * 64 + ks * 32 + quad * 8]);
        bfr[t] = *(const bf16x8*)(&Bs[(wn + t * 16 + l16) * 64 + ks * 32 + quad * 8]);
      }
#pragma unroll
      for (int mt = 0; mt < 4; mt++)
#pragma unroll
        for (int nt = 0; nt < 4; nt++)
          acc[mt][nt] = __builtin_amdgcn_mfma_f32_16x16x32_bf16(af[mt], bfr[nt], acc[mt][nt], 0, 0, 0);
    }
  }
#pragma unroll
  for (int mt = 0; mt < 4; mt++)
#pragma unroll
    for (int r = 0; r < 4; r++){
      int row = m0 + wm + mt * 16 + quad * 4 + r;
      float invL = 1.f / rowsum[row];
#pragma unroll
      for (int nt = 0; nt < 4; nt++){
        int col = d0 + wn + nt * 16 + l16;
        size_t idx = (size_t)row * CDIM + col;
        float v = acc[mt][nt][r] * invL + b2f(planes[idx]) + b2f(planes[(size_t)S_LEN * CDIM + idx]);
        attnS[idx] = f2bf(v);
      }
    }
}

extern "C" void kernel_launch(void* const* d_in, const int* in_sizes, int n_in,
                              void* d_out, int out_size, void* d_ws, size_t ws_size,
                              hipStream_t stream){
  const float* hs  = (const float*)d_in[0];
  const int* mask  = (const int*)d_in[1];
  const int* inp   = (const int*)d_in[2];
  char* ws = (char*)d_ws;
  int*            labels  = (int*)(ws + 0);
  int*            perm    = (int*)(ws + 16896);
  int*            inv     = (int*)(ws + 33280);
  int*            labP    = (int*)(ws + 49664);
  int4*           qtinfo  = (int4*)(ws + 66560);
  float*          rowsum  = (float*)(ws + 67072);
  unsigned short* hsb     = (unsigned short*)(ws + 131072);
  unsigned short* Wall    = (unsigned short*)(ws + 5373952);
  unsigned short* proj    = (unsigned short*)(ws + 13565952);
  unsigned short* vT      = (unsigned short*)(ws + 60751872);
  unsigned short* planes  = (unsigned short*)(ws + 76480512);   // 2 bf16 planes = 10.5 MB
  unsigned short* Sbuf    = (unsigned short*)(ws + 86966272);   // up to 1024 tiles * 32 KB
  unsigned short* attnS   = (unsigned short*)(ws + 120520704);
  unsigned short* Wob     = Wall + 9 * 409600;
  // attn partials live in the Sbuf region (consumed by k_comb BEFORE k_ent_qk
  // overwrites Sbuf): opart = 6 x [4096][640] bf16 (31.5 MB), lpP = 6x8x4096 f32.
  unsigned short* opart   = Sbuf;
  float*          lpP     = (float*)(ws + 86966272 + 31457280);

  k_prep<<<1, 1024, 0, stream>>>(mask, inp, labels, perm, inv, labP, qtinfo, rowsum);
  WPtrs wp;
  for (int i = 0; i < 10; i++) wp.w[i] = (const float*)d_in[3 + i];
  k_cvt_all<<<2560 + 4000, 256, 0, stream>>>(hs, wp, hsb, Wall);

  // all 9 projections in one GEMM, rows scattered into bucket-permuted order
  k_gemm<0><<<dim3(45, 32), 256, 0, stream>>>(hsb, Wall, S_LEN, NPROJ, CDIM, NPROJ,
                                              inv, proj, nullptr, nullptr);
  k_transpose_v<<<dim3(64, 10, 3), 256, 0, stream>>>(proj, vT);

  // branches 1+3: 256-query 8-wave blocks + 3-way key split; partials + combine
  k_attn80<<<dim3(48, 8, 2), 512, 0, stream>>>(proj, vT, labP, qtinfo, opart, lpP);
  k_comb<<<dim3(2560, 2), 256, 0, stream>>>(opart, lpP, planes);

  // branch 2 (entity, d=640): GEMM-ified, P materialized bf16 per bucket
  k_ent_qk<<<dim3(32, 32), 256, 0, stream>>>(proj, labP, qtinfo, Sbuf, rowsum);
  k_ent_pv<<<dim3(5, 32), 256, 0, stream>>>(Sbuf, vT + (size_t)1 * CDIM * S_LEN,
                                            qtinfo, rowsum, planes, attnS);

  // out = attnS @ Wo^T + residual, un-permuted via perm in the epilogue
  k_gemm<1><<<dim3(5, 32), 256, 0, stream>>>(attnS, Wob, S_LEN, CDIM, CDIM, CDIM,
                                             perm, nullptr, (float*)d_out, hs);
}